// Round 1
// baseline (2388.606 us; speedup 1.0000x reference)
//
#include <hip/hip_runtime.h>
#include <math.h>

// Problem constants
constexpr int BATCH = 256;
constexpr int SEQ   = 128;
constexpr int FEAT  = 512;
constexpr int HID   = 512;
constexpr int G3    = 1536;   // 3*HID

// ---------------------------------------------------------------------------
// Input projection: xp[m][n] = sum_k x[m][k] * Wk[k][n] + bi[n]
//   m = b*SEQ + t (natural x row order), n in [0,1536)
// BM=128, BN=64, BK=16, 256 threads, thread tile 8x4.
// ---------------------------------------------------------------------------
__global__ __launch_bounds__(256) void proj_kernel(
    const float* __restrict__ x, const float* __restrict__ Wk,
    const float* __restrict__ bias, float* __restrict__ xp)
{
  __shared__ float As[16][132];   // [k][m], padded
  __shared__ float Bs[16][68];    // [k][n], padded

  const int tid = threadIdx.x;
  const int m0 = blockIdx.y * 128;
  const int n0 = blockIdx.x * 64;
  const int ty = tid >> 4;        // 0..15 -> rows ty*8..+7
  const int tx = tid & 15;        // 0..15 -> cols tx*4..+3

  float acc[8][4] = {};

  for (int k0 = 0; k0 < FEAT; k0 += 16) {
    __syncthreads();
    // load x tile: 128 rows x 16 k = 512 float4, 2 per thread
#pragma unroll
    for (int i = 0; i < 2; ++i) {
      int q  = tid + i * 256;          // 0..511
      int r  = q >> 2;                 // 0..127
      int k4 = q & 3;                  // 0..3
      float4 v = *(const float4*)&x[(size_t)(m0 + r) * FEAT + k0 + k4 * 4];
      As[k4 * 4 + 0][r] = v.x;
      As[k4 * 4 + 1][r] = v.y;
      As[k4 * 4 + 2][r] = v.z;
      As[k4 * 4 + 3][r] = v.w;
    }
    // load Wk tile: 16 k x 64 n = 256 float4, 1 per thread
    {
      int kr = tid >> 4;
      int c4 = tid & 15;
      float4 v = *(const float4*)&Wk[(size_t)(k0 + kr) * G3 + n0 + c4 * 4];
      *(float4*)&Bs[kr][c4 * 4] = v;
    }
    __syncthreads();
#pragma unroll
    for (int k = 0; k < 16; ++k) {
      float a0[8], b0[4];
      *(float4*)&a0[0] = *(const float4*)&As[k][ty * 8];
      *(float4*)&a0[4] = *(const float4*)&As[k][ty * 8 + 4];
      *(float4*)&b0[0] = *(const float4*)&Bs[k][tx * 4];
#pragma unroll
      for (int i = 0; i < 8; ++i)
#pragma unroll
        for (int j = 0; j < 4; ++j)
          acc[i][j] += a0[i] * b0[j];
    }
  }

#pragma unroll
  for (int i = 0; i < 8; ++i) {
    int m = m0 + ty * 8 + i;
    float4 v;
    v.x = acc[i][0] + bias[n0 + tx * 4 + 0];
    v.y = acc[i][1] + bias[n0 + tx * 4 + 1];
    v.z = acc[i][2] + bias[n0 + tx * 4 + 2];
    v.w = acc[i][3] + bias[n0 + tx * 4 + 3];
    *(float4*)&xp[(size_t)m * G3 + n0 + tx * 4] = v;
  }
}

// ---------------------------------------------------------------------------
// One GRU step. h stored TRANSPOSED in global: hT[k][b] (k<512, b<256).
// Block: 16 batch rows x 32 j-cols (x3 gates). Grid (16 jt, 16 mt) = 256.
// 4 waves split K (wave w takes k === w mod 4); LDS reduction at the end.
// ---------------------------------------------------------------------------
__global__ __launch_bounds__(256) void gru_step(
    const float* __restrict__ hTin,   // [512][256]
    float* __restrict__ hTout,        // [512][256]
    const float* __restrict__ xp,     // [(b*SEQ+t)][1536], bias included
    const float* __restrict__ Wr,     // [512][1536]
    const float* __restrict__ br,     // recurrent bias [1536]
    int t)
{
  __shared__ float hTs[512][20];      // [k][r local], 40 KB
  __shared__ float Ws[128][100];      // K-chunk of Wr cols, 51.2 KB
  __shared__ float red[4][16 * 97];   // per-wave partials, 24.8 KB

  const int tid  = threadIdx.x;
  const int wave = tid >> 6;
  const int lane = tid & 63;
  const int rgrp = lane >> 4;         // rows rgrp*4..+3
  const int cgrp = lane & 15;         // cols cgrp*2, cgrp*2+1 (per gate)
  const int m0 = blockIdx.y * 16;
  const int j0 = blockIdx.x * 32;

  // stage h tile (transposed source -> conflict-free LDS writes)
#pragma unroll
  for (int i = 0; i < 8; ++i) {
    int q  = tid + i * 256;           // 0..2047
    int k  = q >> 2;                  // 0..511
    int c4 = (q & 3) * 4;             // 0,4,8,12
    float4 v = *(const float4*)&hTin[k * BATCH + m0 + c4];
    *(float4*)&hTs[k][c4] = v;
  }

  float acc[3][4][2] = {};            // [gate][row][col]

  for (int ch = 0; ch < 4; ++ch) {
    __syncthreads();                  // Ws reuse guard (+ hTs ready at ch=0)
    // stage Wr chunk: 128 k x 96 cols = 3072 float4, 12 per thread
#pragma unroll
    for (int i = 0; i < 12; ++i) {
      int q   = tid + i * 256;        // 0..3071
      int kr  = q / 24;               // 24 f4 per row
      int rem = q - kr * 24;
      int g   = rem >> 3;             // gate 0..2
      int c4  = (rem & 7) * 4;        // 0..28
      float4 v = *(const float4*)&Wr[(size_t)(ch * 128 + kr) * G3 + g * 512 + j0 + c4];
      *(float4*)&Ws[kr][g * 32 + c4] = v;
    }
    __syncthreads();

#pragma unroll 8
    for (int i = 0; i < 32; ++i) {
      int kk = (i << 2) | wave;       // 0..127
      int k  = (ch << 7) | kk;        // global k
      float4 hv = *(const float4*)&hTs[k][rgrp * 4];
      float2 wz = *(const float2*)&Ws[kk][cgrp * 2];
      float2 wr2 = *(const float2*)&Ws[kk][32 + cgrp * 2];
      float2 wh = *(const float2*)&Ws[kk][64 + cgrp * 2];
      float hvv[4] = {hv.x, hv.y, hv.z, hv.w};
#pragma unroll
      for (int r = 0; r < 4; ++r) {
        acc[0][r][0] += hvv[r] * wz.x;  acc[0][r][1] += hvv[r] * wz.y;
        acc[1][r][0] += hvv[r] * wr2.x; acc[1][r][1] += hvv[r] * wr2.y;
        acc[2][r][0] += hvv[r] * wh.x;  acc[2][r][1] += hvv[r] * wh.y;
      }
    }
  }

  // cross-wave reduction via LDS
#pragma unroll
  for (int g = 0; g < 3; ++g)
#pragma unroll
    for (int r = 0; r < 4; ++r)
#pragma unroll
      for (int c = 0; c < 2; ++c) {
        int row = rgrp * 4 + r;
        int col = g * 32 + cgrp * 2 + c;
        red[wave][row * 97 + col] = acc[g][r][c];
      }
  __syncthreads();

  // epilogue: 512 h-updates (16 rows x 32 j), 2 per thread
#pragma unroll
  for (int p = 0; p < 2; ++p) {
    int idx = tid + p * 256;          // 0..511
    int r  = idx & 15;
    int ji = idx >> 4;                // 0..31
    int b  = m0 + r;
    int j  = j0 + ji;

    float rz = red[0][r * 97 + ji]       + red[1][r * 97 + ji]
             + red[2][r * 97 + ji]       + red[3][r * 97 + ji];
    float rr = red[0][r * 97 + 32 + ji]  + red[1][r * 97 + 32 + ji]
             + red[2][r * 97 + 32 + ji]  + red[3][r * 97 + 32 + ji];
    float rh = red[0][r * 97 + 64 + ji]  + red[1][r * 97 + 64 + ji]
             + red[2][r * 97 + 64 + ji]  + red[3][r * 97 + 64 + ji];

    rz += br[j];
    rr += br[512 + j];
    rh += br[1024 + j];

    size_t xb = ((size_t)b * SEQ + t) * G3;
    float xz = xp[xb + j];
    float xr = xp[xb + 512 + j];
    float xh = xp[xb + 1024 + j];

    float hold = hTin[j * BATCH + b];

    float z  = 1.f / (1.f + __expf(-(xz + rz)));
    float rg = 1.f / (1.f + __expf(-(xr + rr)));
    float hh = fmaxf(xh + rg * rh, 0.f);

    hTout[j * BATCH + b] = z * hold + (1.f - z) * hh;
  }
}

// ---------------------------------------------------------------------------
// Dense head: out[b] = sum_k hT[k][b] * Wd[k] + bd
// ---------------------------------------------------------------------------
__global__ __launch_bounds__(256) void head_kernel(
    const float* __restrict__ hT, const float* __restrict__ Wd,
    const float* __restrict__ bd, float* __restrict__ out)
{
  int b = threadIdx.x;                // 256 threads
  float s = 0.f;
#pragma unroll 8
  for (int k = 0; k < HID; ++k)
    s += hT[k * BATCH + b] * Wd[k];
  out[b] = s + bd[0];
}

// ---------------------------------------------------------------------------
extern "C" void kernel_launch(void* const* d_in, const int* in_sizes, int n_in,
                              void* d_out, int out_size, void* d_ws, size_t ws_size,
                              hipStream_t stream) {
  const float* x    = (const float*)d_in[0];
  const float* Wk   = (const float*)d_in[1];
  const float* Wr   = (const float*)d_in[2];
  const float* bias = (const float*)d_in[3];
  const float* Wd   = (const float*)d_in[4];
  const float* bd   = (const float*)d_in[5];
  float* out = (float*)d_out;

  char* ws = (char*)d_ws;
  float* xp = (float*)ws;                                   // 256*128*1536 f32 = 201.3 MB
  float* hA = (float*)(ws + (size_t)BATCH * SEQ * G3 * 4);  // hT buffers [512][256]
  float* hB = hA + (size_t)HID * BATCH;

  // h0 = 0
  hipMemsetAsync(hA, 0, (size_t)HID * BATCH * sizeof(float), stream);

  // input projection
  dim3 pgrid(G3 / 64, (BATCH * SEQ) / 128);   // 24 x 256
  proj_kernel<<<pgrid, 256, 0, stream>>>(x, Wk, bias, xp);

  // recurrence
  const float* br = bias + G3;
  for (int t = 0; t < SEQ; ++t) {
    const float* hin = (t & 1) ? hB : hA;
    float*       hout = (t & 1) ? hA : hB;
    gru_step<<<dim3(16, 16), 256, 0, stream>>>(hin, hout, xp, Wr, br, t);
  }
  // SEQ=128 steps: last step t=127 (odd) wrote hA

  head_kernel<<<1, 256, 0, stream>>>(hA, Wd, bd, out);
}

// Round 2
// 688.071 us; speedup vs baseline: 3.4715x; 3.4715x over previous
//
#include <hip/hip_runtime.h>
#include <hip/hip_bf16.h>
#include <math.h>

constexpr int BATCH = 256;
constexpr int SEQ   = 128;
constexpr int FEAT  = 512;
constexpr int HID   = 512;
constexpr int G3    = 1536;

typedef __bf16 bf16x8 __attribute__((ext_vector_type(8)));
typedef float  f32x4  __attribute__((ext_vector_type(4)));

// ---------------------------------------------------------------------------
// fp32 -> bf16 convert (vectorized, 8/thread)
// ---------------------------------------------------------------------------
__global__ __launch_bounds__(256) void convert_bf16(
    const float* __restrict__ in, __hip_bfloat16* __restrict__ out, int n)
{
  int i = (blockIdx.x * 256 + threadIdx.x) * 8;
  if (i >= n) return;
  float4 v0 = *(const float4*)&in[i];
  float4 v1 = *(const float4*)&in[i + 4];
  __hip_bfloat16 o[8];
  o[0] = (__hip_bfloat16)v0.x; o[1] = (__hip_bfloat16)v0.y;
  o[2] = (__hip_bfloat16)v0.z; o[3] = (__hip_bfloat16)v0.w;
  o[4] = (__hip_bfloat16)v1.x; o[5] = (__hip_bfloat16)v1.y;
  o[6] = (__hip_bfloat16)v1.z; o[7] = (__hip_bfloat16)v1.w;
  *(int4*)&out[i] = *(int4*)o;
}

// ---------------------------------------------------------------------------
// transpose + convert: in[512][1536] f32 -> outT[1536][512] bf16
// ---------------------------------------------------------------------------
__global__ __launch_bounds__(256) void transpose_convert(
    const float* __restrict__ in, __hip_bfloat16* __restrict__ outT)
{
  __shared__ float tile[32][33];
  const int c0 = blockIdx.x * 32;   // column tile in input (row tile in output)
  const int r0 = blockIdx.y * 32;   // row tile in input
  const int tid = threadIdx.x;
  {
    int row = tid >> 3, c4 = tid & 7;
    float4 v = *(const float4*)&in[(size_t)(r0 + row) * G3 + c0 + c4 * 4];
    tile[row][c4 * 4 + 0] = v.x;
    tile[row][c4 * 4 + 1] = v.y;
    tile[row][c4 * 4 + 2] = v.z;
    tile[row][c4 * 4 + 3] = v.w;
  }
  __syncthreads();
  {
    int rowT = tid >> 3, c4 = tid & 7;   // output row = c0+rowT, k offset r0+c4*4
    __hip_bfloat16 o[4];
#pragma unroll
    for (int e = 0; e < 4; ++e)
      o[e] = (__hip_bfloat16)tile[c4 * 4 + e][rowT];
    *(int2*)&outT[(size_t)(c0 + rowT) * FEAT + r0 + c4 * 4] = *(int2*)o;
  }
}

// ---------------------------------------------------------------------------
// proj: xp[m][n] (bf16) = xb[m][:] @ Wk[:, n] + bi[n]
//   A = xb [32768][512] bf16 row-major, B^T = WkT [1536][512] bf16 row-major.
// 128x128 tile, 4 waves (2x2), each 64x64 via 4x4 MFMA 16x16x32 frags.
// ---------------------------------------------------------------------------
__global__ __launch_bounds__(256) void proj_mfma(
    const __hip_bfloat16* __restrict__ xb, const __hip_bfloat16* __restrict__ WkT,
    const float* __restrict__ bias, __hip_bfloat16* __restrict__ xp)
{
  __shared__ __align__(16) __hip_bfloat16 As[128][72];  // +8 pad: stride 144B
  __shared__ __align__(16) __hip_bfloat16 Bs[128][72];

  const int tid = threadIdx.x;
  const int wave = tid >> 6, l = tid & 63;
  const int wm = wave >> 1, wn = wave & 1;       // wave tile: 64x64
  const int m0 = blockIdx.y * 128;
  const int n0 = blockIdx.x * 128;
  const int lr = l & 15, lk = (l >> 4) * 8;      // fragment row / k-offset

  f32x4 acc[4][4] = {};

  for (int k0 = 0; k0 < FEAT; k0 += 64) {
    __syncthreads();
#pragma unroll
    for (int i = 0; i < 4; ++i) {                // A tile: 128x64 bf16
      int q = tid + i * 256;                     // 0..1023
      int row = q >> 3, c = q & 7;
      *(int4*)&As[row][c * 8] =
          *(const int4*)&xb[(size_t)(m0 + row) * FEAT + k0 + c * 8];
    }
#pragma unroll
    for (int i = 0; i < 4; ++i) {                // B tile: 128x64 bf16 (B^T rows)
      int q = tid + i * 256;
      int row = q >> 3, c = q & 7;
      *(int4*)&Bs[row][c * 8] =
          *(const int4*)&WkT[(size_t)(n0 + row) * FEAT + k0 + c * 8];
    }
    __syncthreads();

#pragma unroll
    for (int ks = 0; ks < 2; ++ks) {             // two K=32 steps per BK=64
      bf16x8 a[4], b[4];
#pragma unroll
      for (int i = 0; i < 4; ++i)
        a[i] = *(const bf16x8*)&As[wm * 64 + i * 16 + lr][ks * 32 + lk];
#pragma unroll
      for (int j = 0; j < 4; ++j)
        b[j] = *(const bf16x8*)&Bs[wn * 64 + j * 16 + lr][ks * 32 + lk];
#pragma unroll
      for (int i = 0; i < 4; ++i)
#pragma unroll
        for (int j = 0; j < 4; ++j)
          acc[i][j] = __builtin_amdgcn_mfma_f32_16x16x32_bf16(a[i], b[j], acc[i][j], 0, 0, 0);
    }
  }

  // epilogue: bias add, bf16 store. D: row=(l>>4)*4+r, col=l&15
  float bv[4];
#pragma unroll
  for (int j = 0; j < 4; ++j)
    bv[j] = bias[n0 + wn * 64 + j * 16 + lr];
#pragma unroll
  for (int i = 0; i < 4; ++i)
#pragma unroll
    for (int j = 0; j < 4; ++j) {
      int n = n0 + wn * 64 + j * 16 + lr;
#pragma unroll
      for (int r = 0; r < 4; ++r) {
        int m = m0 + wm * 64 + i * 16 + (l >> 4) * 4 + r;
        xp[(size_t)m * G3 + n] = (__hip_bfloat16)(acc[i][j][r] + bv[j]);
      }
    }
}

// ---------------------------------------------------------------------------
// One GRU step, MFMA. Block = 16 rows x 16 j-cols (x3 gates => N=48).
// Grid (32 jb, 16 mb) = 512 blocks, 4 waves split K=512 by 128 each.
// hb_in/hb_out: bf16 [256][512] double-buffered. h32: fp32 [256][512] in-place.
// ---------------------------------------------------------------------------
__global__ __launch_bounds__(256) void gru_step_mfma(
    const __hip_bfloat16* __restrict__ hb_in, __hip_bfloat16* __restrict__ hb_out,
    float* __restrict__ h32,
    const __hip_bfloat16* __restrict__ xp,   // [(b*SEQ+t)][1536] bf16 (bias incl.)
    const __hip_bfloat16* __restrict__ WrT,  // [1536][512] bf16
    const float* __restrict__ br, int t)
{
  __shared__ __align__(16) __hip_bfloat16 h_s[16][520];   // 16.6 KB
  __shared__ __align__(16) __hip_bfloat16 W_s[48][520];   // 49.9 KB
  __shared__ float red[4][16][48];                        // 12.3 KB

  const int tid = threadIdx.x;
  const int wave = tid >> 6, l = tid & 63;
  const int jb = blockIdx.x;        // 0..31, 16 j-cols
  const int m0 = blockIdx.y * 16;   // row tile

  // stage h rows (bf16, coalesced): 16 x 512 = 1024 x 16B chunks
#pragma unroll
  for (int i = 0; i < 4; ++i) {
    int q = tid + i * 256;
    int r = q >> 6, c = q & 63;
    *(int4*)&h_s[r][c * 8] = *(const int4*)&hb_in[(size_t)(m0 + r) * HID + c * 8];
  }
  // stage WrT rows for our 48 output cols: n = g*512 + jb*16 + cc
#pragma unroll
  for (int i = 0; i < 12; ++i) {
    int q = tid + i * 256;          // 0..3071
    int row = q >> 6, c = q & 63;   // row 0..47
    int n = (row >> 4) * HID + jb * 16 + (row & 15);
    *(int4*)&W_s[row][c * 8] = *(const int4*)&WrT[(size_t)n * HID + c * 8];
  }
  __syncthreads();

  f32x4 acc[3] = {};
  const int lr = l & 15;
#pragma unroll
  for (int ks = 0; ks < 4; ++ks) {
    int k = wave * 128 + ks * 32 + (l >> 4) * 8;
    bf16x8 a = *(const bf16x8*)&h_s[lr][k];
#pragma unroll
    for (int g = 0; g < 3; ++g) {
      bf16x8 b = *(const bf16x8*)&W_s[g * 16 + lr][k];
      acc[g] = __builtin_amdgcn_mfma_f32_16x16x32_bf16(a, b, acc[g], 0, 0, 0);
    }
  }

  // per-wave partials -> LDS
#pragma unroll
  for (int g = 0; g < 3; ++g)
#pragma unroll
    for (int i = 0; i < 4; ++i)
      red[wave][(l >> 4) * 4 + i][g * 16 + lr] = acc[g][i];
  __syncthreads();

  // epilogue: one (b, j) per thread
  {
    int m = tid >> 4, c = tid & 15;
    int b = m0 + m, j = jb * 16 + c;
    float rz = red[0][m][c]      + red[1][m][c]      + red[2][m][c]      + red[3][m][c];
    float rr = red[0][m][16 + c] + red[1][m][16 + c] + red[2][m][16 + c] + red[3][m][16 + c];
    float rh = red[0][m][32 + c] + red[1][m][32 + c] + red[2][m][32 + c] + red[3][m][32 + c];
    rz += br[j];
    rr += br[HID + j];
    rh += br[2 * HID + j];

    size_t xbase = ((size_t)b * SEQ + t) * G3;
    float xz = (float)xp[xbase + j];
    float xr = (float)xp[xbase + HID + j];
    float xh = (float)xp[xbase + 2 * HID + j];

    float hold = h32[(size_t)b * HID + j];
    float z  = 1.f / (1.f + __expf(-(xz + rz)));
    float rg = 1.f / (1.f + __expf(-(xr + rr)));
    float hh = fmaxf(xh + rg * rh, 0.f);
    float hnew = z * hold + (1.f - z) * hh;

    h32[(size_t)b * HID + j] = hnew;
    hb_out[(size_t)b * HID + j] = (__hip_bfloat16)hnew;
  }
}

// ---------------------------------------------------------------------------
// head: out[b] = h32[b][:] . Wd + bd    (256 blocks x 1 wave)
// ---------------------------------------------------------------------------
__global__ __launch_bounds__(64) void head_kernel(
    const float* __restrict__ h32, const float* __restrict__ Wd,
    const float* __restrict__ bd, float* __restrict__ out)
{
  int b = blockIdx.x, l = threadIdx.x;
  const float* hr = &h32[(size_t)b * HID];
  float s = 0.f;
#pragma unroll
  for (int i = 0; i < 8; ++i)
    s += hr[l + i * 64] * Wd[l + i * 64];
#pragma unroll
  for (int off = 32; off; off >>= 1) s += __shfl_down(s, off);
  if (l == 0) out[b] = s + bd[0];
}

// ---------------------------------------------------------------------------
extern "C" void kernel_launch(void* const* d_in, const int* in_sizes, int n_in,
                              void* d_out, int out_size, void* d_ws, size_t ws_size,
                              hipStream_t stream) {
  const float* x    = (const float*)d_in[0];
  const float* Wk   = (const float*)d_in[1];
  const float* Wr   = (const float*)d_in[2];
  const float* bias = (const float*)d_in[3];
  const float* Wd   = (const float*)d_in[4];
  const float* bd   = (const float*)d_in[5];
  float* out = (float*)d_out;

  char* ws = (char*)d_ws;
  size_t off = 0;
  __hip_bfloat16* xp  = (__hip_bfloat16*)(ws + off); off += (size_t)BATCH * SEQ * G3 * 2;   // 100.7 MB
  __hip_bfloat16* xb  = (__hip_bfloat16*)(ws + off); off += (size_t)BATCH * SEQ * FEAT * 2; // 33.6 MB
  __hip_bfloat16* WkT = (__hip_bfloat16*)(ws + off); off += (size_t)G3 * FEAT * 2;
  __hip_bfloat16* WrT = (__hip_bfloat16*)(ws + off); off += (size_t)G3 * HID * 2;
  float*          h32 = (float*)(ws + off);          off += (size_t)BATCH * HID * 4;
  __hip_bfloat16* hb0 = (__hip_bfloat16*)(ws + off); off += (size_t)BATCH * HID * 2;
  __hip_bfloat16* hb1 = (__hip_bfloat16*)(ws + off); off += (size_t)BATCH * HID * 2;

  // converts / transposes
  convert_bf16<<<(BATCH * SEQ * FEAT) / (256 * 8), 256, 0, stream>>>(x, xb, BATCH * SEQ * FEAT);
  transpose_convert<<<dim3(G3 / 32, FEAT / 32), 256, 0, stream>>>(Wk, WkT);
  transpose_convert<<<dim3(G3 / 32, HID  / 32), 256, 0, stream>>>(Wr, WrT);

  // projection GEMM (bias folded in)
  proj_mfma<<<dim3(G3 / 128, (BATCH * SEQ) / 128), 256, 0, stream>>>(xb, WkT, bias, xp);

  // h0 = 0
  hipMemsetAsync(h32, 0, (size_t)BATCH * HID * sizeof(float), stream);
  hipMemsetAsync(hb0, 0, (size_t)BATCH * HID * sizeof(__hip_bfloat16), stream);

  const float* br = bias + G3;
  for (int t = 0; t < SEQ; ++t) {
    const __hip_bfloat16* hin = (t & 1) ? hb1 : hb0;
    __hip_bfloat16*      hout = (t & 1) ? hb0 : hb1;
    gru_step_mfma<<<dim3(32, 16), 256, 0, stream>>>(hin, hout, h32, xp, WrT, br, t);
  }

  head_kernel<<<256, 64, 0, stream>>>(h32, Wd, bd, out);
}